// Round 9
// baseline (90.282 us; speedup 1.0000x reference)
//
#include <hip/hip_runtime.h>
#include <hip/hip_bf16.h>

#define T_LEN 2048
#define NBATCH 32

typedef __bf16 bf16x8 __attribute__((ext_vector_type(8)));
typedef float f32x4 __attribute__((ext_vector_type(4)));

__device__ __forceinline__ unsigned short f2bf(float f) {
  return __builtin_bit_cast(unsigned short, __float2bfloat16(f));
}
__device__ __forceinline__ unsigned int pk2(float a, float b) {
  return (unsigned int)f2bf(a) | ((unsigned int)f2bf(b) << 16);
}
__device__ __forceinline__ bf16x8 ld16(const void* p) {
  return __builtin_bit_cast(bf16x8, *(const uint4*)p);
}
// async global->LDS, 16B per lane: lds dest = uniform base + lane*16 (linear),
// global src is PER-LANE (pre-swizzled by caller).
__device__ __forceinline__ void gl_lds16(const void* g, void* l) {
  __builtin_amdgcn_global_load_lds(
      (const __attribute__((address_space(1))) unsigned int*)g,
      (__attribute__((address_space(3))) unsigned int*)l, 16, 0, 0);
}
// raw barrier WITHOUT the vmcnt(0) drain __syncthreads() implies.
__device__ __forceinline__ void bar_raw() {
  asm volatile("s_barrier" ::: "memory");
}

// ---------------- Kernel 0: W -> Wt3 bf16 [192][384] (col-major over N) --------
__global__ __launch_bounds__(256) void k_wprep(const float* __restrict__ Wq,
                                               const float* __restrict__ Wk,
                                               const float* __restrict__ Wv,
                                               unsigned short* __restrict__ Wt3) {
  int idx = blockIdx.x * 256 + threadIdx.x;   // 0 .. 192*384-1
  if (idx >= 192 * 384) return;
  int c = idx / 384;          // output col 0..191
  int k = idx % 384;          // k dim
  const float* W = (c < 64) ? Wq : ((c < 128) ? Wk : Wv);
  Wt3[idx] = f2bf(W[k * 64 + (c & 63)]);
}

// ---------------- Kernel 1: QKV projection (MFMA bf16) -------------------------
// x fp32 [B*T][384] -> Q,K bf16 [B*T][64], VT bf16 [B][64][T]
__global__ __launch_bounds__(256) void k_proj(const float* __restrict__ x,
                                              const unsigned short* __restrict__ Wt3,
                                              unsigned short* __restrict__ Qb,
                                              unsigned short* __restrict__ Kb,
                                              unsigned short* __restrict__ VTb) {
  __shared__ __align__(16) unsigned short xs[128 * 32];   // swizzled
  __shared__ __align__(16) unsigned short wt[192 * 32];   // swizzled
  const int tid = threadIdx.x;
  const int lane = tid & 63, w = tid >> 6;
  const int g = lane >> 4, lr = lane & 15;
  const long row0 = (long)blockIdx.x * 128;

  f32x4 acc[2][12] = {};

  for (int ks = 0; ks < 12; ++ks) {
    const int k0 = ks * 32;
    __syncthreads();
    // stage x tile [128][32] fp32->bf16
    {
      int r = tid >> 1, c0 = (tid & 1) * 16;
      const float4* src = reinterpret_cast<const float4*>(&x[(row0 + r) * 384 + k0 + c0]);
      float4 f0 = src[0], f1 = src[1], f2 = src[2], f3 = src[3];
      uint4 u0, u1;
      u0.x = pk2(f0.x, f0.y); u0.y = pk2(f0.z, f0.w);
      u0.z = pk2(f1.x, f1.y); u0.w = pk2(f1.z, f1.w);
      u1.x = pk2(f2.x, f2.y); u1.y = pk2(f2.z, f2.w);
      u1.z = pk2(f3.x, f3.y); u1.w = pk2(f3.z, f3.w);
      int b0 = (r * 64 + c0 * 2) ^ ((r & 7) << 4);
      int b1 = (r * 64 + c0 * 2 + 16) ^ ((r & 7) << 4);
      *reinterpret_cast<uint4*>((char*)xs + b0) = u0;
      *reinterpret_cast<uint4*>((char*)xs + b1) = u1;
    }
    // stage Wt3 tile [192 cols][32 k]
#pragma unroll
    for (int j = 0; j < 3; ++j) {
      int chunk = tid + 256 * j;        // 0..767
      int r = chunk >> 2, c8 = chunk & 3;
      uint4 d = *reinterpret_cast<const uint4*>(&Wt3[r * 384 + k0 + c8 * 8]);
      int b = (r * 64 + c8 * 16) ^ ((r & 7) << 4);
      *reinterpret_cast<uint4*>((char*)wt + b) = d;
    }
    __syncthreads();

    bf16x8 a[2];
#pragma unroll
    for (int mt = 0; mt < 2; ++mt) {
      int r = w * 32 + mt * 16 + lr;
      a[mt] = ld16((char*)xs + ((r * 64 + g * 16) ^ ((r & 7) << 4)));
    }
#pragma unroll
    for (int n = 0; n < 12; ++n) {
      int r = n * 16 + lr;
      bf16x8 bb = ld16((char*)wt + ((r * 64 + g * 16) ^ ((r & 7) << 4)));
      acc[0][n] = __builtin_amdgcn_mfma_f32_16x16x32_bf16(a[0], bb, acc[0][n], 0, 0, 0);
      acc[1][n] = __builtin_amdgcn_mfma_f32_16x16x32_bf16(a[1], bb, acc[1][n], 0, 0, 0);
    }
  }

  // epilogue: D layout col = lr, row = g*4 + rr
#pragma unroll
  for (int mt = 0; mt < 2; ++mt)
#pragma unroll
    for (int n = 0; n < 12; ++n)
#pragma unroll
      for (int rr = 0; rr < 4; ++rr) {
        long grow = row0 + w * 32 + mt * 16 + g * 4 + rr;
        int col = n * 16 + lr;
        unsigned short hv = f2bf(acc[mt][n][rr]);
        if (n < 4) {
          Qb[grow * 64 + col] = hv;
        } else if (n < 8) {
          Kb[grow * 64 + (col - 64)] = hv;
        } else {
          long bb_ = grow >> 11;          // / 2048
          long t = grow & 2047;
          VTb[(bb_ * 64 + (col - 128)) * 2048 + t] = hv;
        }
      }
}

// ---------------- Kernel 2: causal flash attention ------------------------------
// ROUND-9: R8 structure + CAUSAL PAIRING for deterministic CU load balance.
// R8's grid (1024 blocks = exactly the 1024 residency slots, cost 1..32 tiles)
// had no backfill: heavy CUs ran ~32 tile-periods while light CUs idled
// (occupancy 26.5%, ~2x wasted). Now each block processes the q-tile PAIR
// (31-p, p) sequentially -> uniform 33 tile-visits/block, 512 blocks, every
// CU identically loaded. Also: softmax folded to base-2 domain (p =
// exp2(fma(s, C2, -m2)), C2 = 0.125*log2e) -> drops the per-element scale
// multiply + scale loop; mask applied only on the diagonal tile.
__global__ __launch_bounds__(256, 4) void k_attn(const unsigned short* __restrict__ Qb,
                                                 const unsigned short* __restrict__ Kb,
                                                 const unsigned short* __restrict__ VTb,
                                                 float* __restrict__ out) {
  __shared__ __align__(16) char ksm[2 * 8192];              // K tiles [64][64]
  __shared__ __align__(16) char vsm[2 * 8192];              // V^T tiles [64][64]
  __shared__ __align__(16) unsigned short psm[4 * 16 * 64]; // per-wave P, swizzled

  const int tid = threadIdx.x;
  const int lane = tid & 63, w = tid >> 6;
  const int g = lane >> 4, lr = lane & 15;
  const int b = blockIdx.x;
  const int p = blockIdx.y;                      // pair index 0..15

  const char* Kg = (const char*)(Kb + (long)b * T_LEN * 64);   // row stride 128 B
  const char* Vg = (const char*)(VTb + (long)b * 64 * 2048);   // row stride 4096 B

  const int lrow = lane >> 3;
  const int lsw = (((lane & 7) ^ lrow) << 4);    // pre-swizzled source col

  const float C2 = 0.125f * 1.44269504f;         // scale folded into log2 domain
  char* pbase = (char*)psm + w * 2048;

  for (int phase = 0; phase < 2; ++phase) {
    const int qt = phase ? p : (31 - p);         // heavy q-tile first
    const int qrow0 = qt * 64 + w * 16;
    const int nkv = qt + 1;

    // Q fragments (A operand): lane holds Q[qrow0+lr][c*32 + g*8 + i]
    bf16x8 qf[2];
#pragma unroll
    for (int c = 0; c < 2; ++c)
      qf[c] = ld16(&Qb[((long)(b * T_LEN + qrow0 + lr)) * 64 + c * 32 + g * 8]);

    f32x4 o[4] = {};
    float m2[4], l_r[4];   // m2 in base-2 domain; l_r per-lane partials
#pragma unroll
    for (int r = 0; r < 4; ++r) { m2[r] = -1e30f; l_r[r] = 0.f; }

    // ---- prologue: stage tile 0 into buffer 0 (4 loads/wave; completion
    // gated by iter-0's vmcnt(4)+barrierB)
    {
      const char* gk = Kg + ((long)(w * 16 + lrow)) * 128 + lsw;
      const char* gv = Vg + ((long)(w * 16 + lrow)) * 4096 + lsw;
      char* kb = ksm + w * 2048;
      char* vb = vsm + w * 2048;
      gl_lds16(gk, kb);             gl_lds16(gk + 8 * 128, kb + 1024);
      gl_lds16(gv, vb);             gl_lds16(gv + 8 * 4096, vb + 1024);
    }

    int cur = 0;
    for (int t = 0; t < nkv; ++t) {
      const int kv0 = t * 64;

      // ---- barrier A: all waves finished reading buf[cur^1] (iter t-1)
      bar_raw();

      // ---- stage(t+1) into buf[cur^1]; gate on stage(t) completion
      if (t + 1 < nkv) {
        const int kv1 = kv0 + 64;
        const char* gk = Kg + ((long)(kv1 + w * 16 + lrow)) * 128 + lsw;
        const char* gv = Vg + ((long)(w * 16 + lrow)) * 4096 + (long)kv1 * 2 + lsw;
        char* kb = ksm + (cur ^ 1) * 8192 + w * 2048;
        char* vb = vsm + (cur ^ 1) * 8192 + w * 2048;
        gl_lds16(gk, kb);           gl_lds16(gk + 8 * 128, kb + 1024);
        gl_lds16(gv, vb);           gl_lds16(gv + 8 * 4096, vb + 1024);
        asm volatile("s_waitcnt vmcnt(4)" ::: "memory");   // stage(t) done, t+1 in flight
      } else {
        asm volatile("s_waitcnt vmcnt(0)" ::: "memory");   // last tile: drain all
      }
      bar_raw();   // barrier B: every wave's stage(t) landed in LDS

      char* kt = ksm + cur * 8192;
      char* vt = vsm + cur * 8192;

      // ---- S = Q K^T (K from LDS, swizzled reads); raw scores (scale folded)
      f32x4 s[4] = {};
      __builtin_amdgcn_s_setprio(1);
#pragma unroll
      for (int c = 0; c < 2; ++c)
#pragma unroll
        for (int n = 0; n < 4; ++n) {
          int r = n * 16 + lr;
          bf16x8 kf = ld16(kt + ((r * 128 + c * 64 + g * 16) ^ ((r & 7) << 4)));
          s[n] = __builtin_amdgcn_mfma_f32_16x16x32_bf16(qf[c], kf, s[n], 0, 0, 0);
        }
      __builtin_amdgcn_s_setprio(0);

      // ---- causal mask (diagonal tile only)
      if (t == qt) {
#pragma unroll
        for (int n = 0; n < 4; ++n)
#pragma unroll
          for (int r = 0; r < 4; ++r) {
            int col = kv0 + n * 16 + lr;
            int rowq = qrow0 + g * 4 + r;
            if (col > rowq) s[n][r] = -1e30f;
          }
      }

      // ---- T13 defer-max online softmax, base-2 domain
      float pm[4];
#pragma unroll
      for (int r = 0; r < 4; ++r)
        pm[r] = fmaxf(fmaxf(s[0][r], s[1][r]), fmaxf(s[2][r], s[3][r]));
      bool need = false;
#pragma unroll
      for (int r = 0; r < 4; ++r) need = need || (pm[r] * C2 > m2[r] + 11.5f);
      if (__any((int)need)) {
#pragma unroll
        for (int r = 0; r < 4; ++r) {
          float mx = pm[r];
          mx = fmaxf(mx, __shfl_xor(mx, 1));
          mx = fmaxf(mx, __shfl_xor(mx, 2));
          mx = fmaxf(mx, __shfl_xor(mx, 4));
          mx = fmaxf(mx, __shfl_xor(mx, 8));
          float mn = fmaxf(m2[r], mx * C2);
          float sc = exp2f(m2[r] - mn);
          m2[r] = mn;
          l_r[r] *= sc;
#pragma unroll
          for (int n = 0; n < 4; ++n) o[n][r] *= sc;
        }
      }
      float pr[4][4];
#pragma unroll
      for (int r = 0; r < 4; ++r)
#pragma unroll
        for (int n = 0; n < 4; ++n) {
          float pv = exp2f(__builtin_fmaf(s[n][r], C2, -m2[r]));
          pr[n][r] = pv;
          l_r[r] += pv;                 // per-lane partial; no shfl here
        }

      // ---- P -> LDS (per-wave buffer; wave-internal write->read, no barrier)
#pragma unroll
      for (int n = 0; n < 4; ++n)
#pragma unroll
        for (int r = 0; r < 4; ++r) {
          int rq = g * 4 + r;
          int col = n * 16 + lr;
          *(unsigned short*)(pbase + ((rq * 128 + col * 2) ^ ((rq & 7) << 4))) = f2bf(pr[n][r]);
        }

      // ---- O += P V (V from LDS)
      bf16x8 pf[2];
#pragma unroll
      for (int c = 0; c < 2; ++c)
        pf[c] = ld16(pbase + ((lr * 128 + c * 64 + g * 16) ^ ((lr & 7) << 4)));
      __builtin_amdgcn_s_setprio(1);
#pragma unroll
      for (int c = 0; c < 2; ++c)
#pragma unroll
        for (int n = 0; n < 4; ++n) {
          int r = n * 16 + lr;
          bf16x8 vf = ld16(vt + ((r * 128 + c * 64 + g * 16) ^ ((r & 7) << 4)));
          o[n] = __builtin_amdgcn_mfma_f32_16x16x32_bf16(pf[c], vf, o[n], 0, 0, 0);
        }
      __builtin_amdgcn_s_setprio(0);

      cur ^= 1;
    }

    // ---- epilogue: reduce l across the 16 lanes, scale + store this q-tile
#pragma unroll
    for (int r = 0; r < 4; ++r) {
      float l = l_r[r];
      l += __shfl_xor(l, 1);
      l += __shfl_xor(l, 2);
      l += __shfl_xor(l, 4);
      l += __shfl_xor(l, 8);
      float inv = 1.0f / l;
#pragma unroll
      for (int n = 0; n < 4; ++n) {
        long rowg = (long)b * T_LEN + qrow0 + g * 4 + r;
        out[rowg * 64 + n * 16 + lr] = o[n][r] * inv;
      }
    }

    // protect next phase's prologue staging from this phase's lagging readers
    bar_raw();
  }
}

// ---------------- launch -------------------------------------------------------
extern "C" void kernel_launch(void* const* d_in, const int* in_sizes, int n_in,
                              void* d_out, int out_size, void* d_ws, size_t ws_size,
                              hipStream_t stream) {
  const float* x  = (const float*)d_in[0];
  const float* Wq = (const float*)d_in[1];
  const float* Wk = (const float*)d_in[2];
  const float* Wv = (const float*)d_in[3];
  float* out = (float*)d_out;

  char* ws = (char*)d_ws;
  unsigned short* Wt3 = (unsigned short*)ws;                          // 294912 B
  unsigned short* Qb  = (unsigned short*)(ws + 0x80000);              // 8 MiB each
  unsigned short* Kb  = (unsigned short*)(ws + 0x80000 + 0x800000);
  unsigned short* VTb = (unsigned short*)(ws + 0x80000 + 0x1000000);

  k_wprep<<<dim3(288), dim3(256), 0, stream>>>(Wq, Wk, Wv, Wt3);
  k_proj<<<dim3(512), dim3(256), 0, stream>>>(x, Wt3, Qb, Kb, VTb);
  // grid: x = batch, y = causal PAIR (31-p, p) -> uniform 33 tiles per block
  k_attn<<<dim3(NBATCH, 16), dim3(256), 0, stream>>>(Qb, Kb, VTb, out);
}